// Round 6
// baseline (440.982 us; speedup 1.0000x reference)
//
#include <hip/hip_runtime.h>

// Problem constants (from reference)
constexpr int   NPTS   = 65536;
constexpr int   NVIEWS = 16;
constexpr int   SZ     = 400;          // IMG_SIZE
constexpr int   PAD    = 5;            // PADDING
constexpr float FOCAL  = 555.555f;
constexpr float SCALE  = 409.0f / 410.0f;  // (Hp-1)/Hp

constexpr long long FEATS_N = (long long)NPTS * NVIEWS * 3 * 25;  // 78,643,200

typedef float vfloat2 __attribute__((ext_vector_type(2)));
typedef float vfloat4 __attribute__((ext_vector_type(4)));

// ---------------------------------------------------------------------------
// Setup: per-view combined projection KM = K @ inv(pose @ flip)[:3,:]
// ---------------------------------------------------------------------------
__global__ void setup_km(const float* __restrict__ poses, float* __restrict__ km) {
    int n = threadIdx.x;
    if (n >= NVIEWS) return;
    const float* A = poses + n * 16;  // row-major 4x4
    float x0 = A[0], x1 = A[4], x2 = A[8];
    float y0 = A[1], y1 = A[5], y2 = A[9];
    float z0 = A[2], z1 = A[6], z2 = A[10];
    float t0 = A[3], t1 = A[7], t2 = A[11];

    float M0[4] = { -x0, -x1, -x2,  (x0 * t0 + x1 * t1 + x2 * t2) };
    float M1[4] = {  y0,  y1,  y2, -(y0 * t0 + y1 * t1 + y2 * t2) };
    float M2[4] = {  z0,  z1,  z2, -(z0 * t0 + z1 * t1 + z2 * t2) };

    const float f = FOCAL, cx = 0.5f * SZ;
    float* o = km + n * 12;
#pragma unroll
    for (int k = 0; k < 4; ++k) o[k]     = f * M0[k] + cx * M2[k];
#pragma unroll
    for (int k = 0; k < 4; ++k) o[4 + k] = f * M1[k] + cx * M2[k];
#pragma unroll
    for (int k = 0; k < 4; ++k) o[8 + k] = M2[k];
}

// ---------------------------------------------------------------------------
// Gated 3-channel fetch from the (conceptually padded) image — identical
// arithmetic to the round-0 verified kernel.
// ---------------------------------------------------------------------------
__device__ __forceinline__ void fetch3(const float* __restrict__ ib, int r, int c,
                                       float& a, float& b, float& d) {
    bool ok = ((unsigned)r < (unsigned)SZ) & ((unsigned)c < (unsigned)SZ);
    int rc = min(max(r, 0), SZ - 1);
    int cc = min(max(c, 0), SZ - 1);
    const float* q = ib + ((long long)rc * SZ + cc) * 3;
    float m = ok ? 1.0f : 0.0f;
    a = q[0] * m;
    b = q[1] * m;
    d = q[2] * m;
}

// ---------------------------------------------------------------------------
// Dense-store feats kernel ("point-major"), round 6 variant:
//   SINGLE CHANGE vs round 5: output stores are PLAIN (through-L2) instead of
//   __builtin_nontemporal_store.
//   Theory: feats has been ~195-200 us across three structurally different
//   versions (scalar gather / coop staging / dense stores) — the invariant is
//   that all output went through nt stores. 315 MB at the implied ~1.6 TB/s
//   is ~1/4 of the 6.44 TB/s the poison fill achieves with plain stores on
//   the same buffer -> nt's L2-bypass streaming path is the suspected cap.
//   Component model says plain-store feats should cost ~65-85 us
//   (writes ~50 us at ~6.4 TB/s, gather/VALU ~25 us, partly overlapped).
//
//   Block = 256 threads = 8 groups of 32 lanes; group g owns point
//   p = blockIdx*8 + g; lanes 0..24 = taps (i,j); loop n = 0..15.
//   Per (p,n): project, 4x fetch3, bilinear, 3 LDS writes at obuf[g][n][c][ij].
//   Then one sync + coalesced contiguous stream-out (38.4 KB/block).
// ---------------------------------------------------------------------------
__global__ __launch_bounds__(256) void feats_dense(const float* __restrict__ pts,
                                                   const float* __restrict__ imgs,
                                                   const float* __restrict__ km,
                                                   float* __restrict__ out) {
    __attribute__((aligned(16))) __shared__ float obuf[8 * 1200];  // 38,400 B

    unsigned b = blockIdx.x;              // 8192 blocks
    unsigned g = threadIdx.x >> 5;        // point group 0..7
    unsigned l = threadIdx.x & 31u;       // lane within group
    unsigned p = b * 8u + g;

    float px = pts[3 * p], py = pts[3 * p + 1], pz = pts[3 * p + 2];

    unsigned i = (l * 205u) >> 10;        // l / 5 (exact for l < 25)
    unsigned j = l - 5u * i;
    bool active = (l < 25u);
    float fi = (float)i, fj = (float)j;

    float* oisl = obuf + g * 1200u;

    for (unsigned n = 0; n < (unsigned)NVIEWS; ++n) {
        const float* k = km + n * 12u;
        float psx = k[0] * px + k[1] * py + k[2]  * pz + k[3];
        float psy = k[4] * px + k[5] * py + k[6]  * pz + k[7];
        float psz = k[8] * px + k[9] * py + k[10] * pz + k[11];
        float inv = __builtin_amdgcn_rcpf(psz);
        float u = psx * inv * (1.0f / SZ);
        float v = psy * inv * (1.0f / SZ);
        u = fminf(fmaxf(u, 0.0f), 1.0f);
        v = fminf(fmaxf(v, 0.0f), 1.0f);
        float x = u * SZ + (float)(PAD - 2);  // + PADDING - CROP_STEP
        float y = v * SZ + (float)(PAD - 2);

        if (active) {
            float r  = (x + fi) * SCALE;
            float cc = (y + fj) * SCALE;
            float r0f = floorf(r);
            float c0f = floorf(cc);
            float wr = r - r0f;
            float wc = cc - c0f;
            int r0 = (int)r0f - PAD;   // original-image row of corner 00
            int c0 = (int)c0f - PAD;

            const float* ib = imgs + (long long)n * (SZ * SZ * 3);
            float a00, b00, d00, a01, b01, d01, a10, b10, d10, a11, b11, d11;
            fetch3(ib, r0,     c0,     a00, b00, d00);
            fetch3(ib, r0,     c0 + 1, a01, b01, d01);
            fetch3(ib, r0 + 1, c0,     a10, b10, d10);
            fetch3(ib, r0 + 1, c0 + 1, a11, b11, d11);

            float w00 = (1.0f - wr) * (1.0f - wc);
            float w01 = (1.0f - wr) * wc;
            float w10 = wr * (1.0f - wc);
            float w11 = wr * wc;

            float o0 = w00 * a00 + w01 * a01 + w10 * a10 + w11 * a11;
            float o1 = w00 * b00 + w01 * b01 + w10 * b10 + w11 * b11;
            float o2 = w00 * d00 + w01 * d01 + w10 * d10 + w11 * d11;

            unsigned base = n * 75u + l;
            oisl[base]       = o0;
            oisl[base + 25u] = o1;
            oisl[base + 50u] = o2;
        }
    }
    __syncthreads();

    // Stream 9600 floats (= 2400 float4) contiguously via PLAIN stores;
    // block span = 38,400 B, base byte offset b*38400 is 16B-aligned.
    const vfloat4* src = (const vfloat4*)obuf;
    vfloat4* dst = (vfloat4*)(out + (size_t)b * 9600u);
    unsigned t = threadIdx.x;
    for (unsigned q = t; q < 2400u; q += 256u)
        dst[q] = src[q];
}

// ---------------------------------------------------------------------------
// coord_norm kernel: out2[n][p][0..1] = 2*clip(ps.xy/ps.z/SZ,0,1) - 1
// (plain stores, same single-variable change)
// ---------------------------------------------------------------------------
__global__ __launch_bounds__(256) void coord_kernel(const float* __restrict__ pts,
                                                    const float* __restrict__ km,
                                                    float* __restrict__ out2) {
    unsigned tid = blockIdx.x * 256u + threadIdx.x;  // 1,048,576 threads exactly
    unsigned p = tid & (NPTS - 1);
    unsigned n = tid >> 16;

    float px = pts[3 * p], py = pts[3 * p + 1], pz = pts[3 * p + 2];
    const float* k = km + n * 12;
    float psx = k[0] * px + k[1] * py + k[2]  * pz + k[3];
    float psy = k[4] * px + k[5] * py + k[6]  * pz + k[7];
    float psz = k[8] * px + k[9] * py + k[10] * pz + k[11];
    float inv = __builtin_amdgcn_rcpf(psz);
    float u = psx * inv * (1.0f / SZ);
    float v = psy * inv * (1.0f / SZ);
    u = fminf(fmaxf(u, 0.0f), 1.0f);
    v = fminf(fmaxf(v, 0.0f), 1.0f);

    vfloat2* o = (vfloat2*)out2;
    vfloat2 val = { 2.0f * u - 1.0f, 2.0f * v - 1.0f };
    o[tid] = val;
}

extern "C" void kernel_launch(void* const* d_in, const int* in_sizes, int n_in,
                              void* d_out, int out_size, void* d_ws, size_t ws_size,
                              hipStream_t stream) {
    const float* points = (const float*)d_in[0];  // (65536, 3)
    const float* images = (const float*)d_in[1];  // (16, 400, 400, 3)
    const float* poses  = (const float*)d_in[2];  // (16, 4, 4)
    float* out = (float*)d_out;
    float* km  = (float*)d_ws;  // 16 * 12 floats

    setup_km<<<1, 64, 0, stream>>>(poses, km);

    // feats: 65536/8 = 8192 blocks of 256 (8 points each, all 16 views)
    feats_dense<<<8192, 256, 0, stream>>>(points, images, km, out);

    // coord_norm: 16*65536 = 1,048,576 threads = 4096 blocks of 256
    coord_kernel<<<4096, 256, 0, stream>>>(points, km, out + FEATS_N);
}